// Round 4
// baseline (221.977 us; speedup 1.0000x reference)
//
#include <hip/hip_runtime.h>

#define HW  (512 * 512)   // 262144 = 2^18
#define NC  16
#define NB  4
#define GW  512

// (B, C, H, W) f32 -> (B*HW, C) f32. One node per lane.
// Reads: 16 coalesced 4B channel streams; writes: 64B contiguous per lane.
__global__ __launch_bounds__(256) void k_transpose(const float* __restrict__ g,
                                                   float* __restrict__ out) {
    int n  = blockIdx.x * 256 + threadIdx.x;      // 0 .. B*HW-1
    int b  = n >> 18;
    int hw = n & (HW - 1);
    const float* gb = g + (size_t)b * NC * HW + hw;
    float vals[NC];
#pragma unroll
    for (int c = 0; c < NC; ++c) vals[c] = gb[(size_t)c * HW];
    float4* dst = (float4*)(out + (size_t)n * NC);
#pragma unroll
    for (int j = 0; j < 4; ++j)
        dst[j] = make_float4(vals[4 * j], vals[4 * j + 1], vals[4 * j + 2], vals[4 * j + 3]);
}

// One edge per lane: gather 2 endpoints x 4 batches x 64B from node_features,
// accumulate |diff| in fp32, write edge_index (exact f32) and edge_attr (f32).
__global__ __launch_bounds__(256) void k_edges(const int* __restrict__ ei,
                                               const float* __restrict__ nf,
                                               float* __restrict__ out_ei,
                                               float* __restrict__ out_attr,
                                               int E) {
    int e = blockIdx.x * 256 + threadIdx.x;
    if (e >= E) return;
    int s = ei[e];
    int d = ei[E + e];

    int dh = (s >> 9) - (d >> 9);
    int dw = (s & (GW - 1)) - (d & (GW - 1));
    float dist = sqrtf((float)(dh * dh + dw * dw));

    float acc = 0.0f;
#pragma unroll
    for (int b = 0; b < NB; ++b) {
        const float4* ps = (const float4*)(nf + (((size_t)b << 18) + (size_t)s) * NC);
        const float4* pd = (const float4*)(nf + (((size_t)b << 18) + (size_t)d) * NC);
#pragma unroll
        for (int j = 0; j < 4; ++j) {
            float4 a = ps[j];
            float4 c = pd[j];
            acc += fabsf(a.x - c.x) + fabsf(a.y - c.y) +
                   fabsf(a.z - c.z) + fabsf(a.w - c.w);
        }
    }
    float fdiff = acc * (1.0f / 64.0f);

    out_ei[e]     = (float)s;    // indices < 2^24: exact in f32
    out_ei[E + e] = (float)d;
    out_attr[2 * e]     = dist;
    out_attr[2 * e + 1] = fdiff;
}

extern "C" void kernel_launch(void* const* d_in, const int* in_sizes, int n_in,
                              void* d_out, int out_size, void* d_ws, size_t ws_size,
                              hipStream_t stream) {
    const float* g  = (const float*)d_in[0];   // f32 grid (B,C,H,W)
    const int*   ei = (const int*)d_in[1];     // int32 edge_index [2,E] flat
    int E = in_sizes[1] / 2;

    float* out      = (float*)d_out;
    float* nf_out   = out;                                   // (B*HW, C)  f32
    float* ei_out   = out + (size_t)NB * HW * NC;            // (2, E)     f32
    float* attr_out = ei_out + (size_t)2 * E;                // (E, 2)     f32

    k_transpose<<<(NB * HW) / 256, 256, 0, stream>>>(g, nf_out);
    k_edges<<<(E + 255) / 256, 256, 0, stream>>>(ei, nf_out, ei_out, attr_out, E);
}

// Round 5
// 220.748 us; speedup vs baseline: 1.0056x; 1.0056x over previous
//
#include <hip/hip_runtime.h>

#define HW  (512 * 512)   // 262144 = 2^18
#define NC  16
#define NB  4
#define GW  512
#define GH  512
#define TILE 16
#define HALO 18           // TILE + 2
#define NSTRIDE 33        // 32 packed uints per node + 1 pad (bank-conflict-free)

// fp32 -> bf16 (RNE), packed helpers
__device__ __forceinline__ unsigned int bfr(float f) {
    union { float f; unsigned int u; } v; v.f = f;
    return (v.u + 0x7fffu + ((v.u >> 16) & 1u)) >> 16;
}
__device__ __forceinline__ unsigned int pack2(float a, float b) {
    return bfr(a) | (bfr(b) << 16);
}
__device__ __forceinline__ float blo(unsigned int u) {
    union { unsigned int u; float f; } v; v.u = u << 16; return v.f;
}
__device__ __forceinline__ float bhi(unsigned int u) {
    union { unsigned int u; float f; } v; v.u = u & 0xffff0000u; return v.f;
}

// edges strictly before node (h,w) in node-major, offset-ordered enumeration.
// degrees: corner 3, edge 5, interior 8. row0/row511 total 2556, interior 4090.
__device__ __forceinline__ int edge_prefix(int h, int w) {
    if (h == 0) return (w == 0) ? 0 : 3 + 5 * (w - 1);
    int p = 2556 + 4090 * (h - 1);
    if (h == GH - 1) return p + ((w == 0) ? 0 : 3 + 5 * (w - 1));
    return p + ((w == 0) ? 0 : 5 + 8 * (w - 1));
}

// (B, C, H, W) f32 -> (B*HW, C) f32. 4 consecutive nodes per thread.
// Reads: 16 x float4 (1 KB/instr/wave); writes: 256B contiguous per lane.
__global__ __launch_bounds__(256) void k_transpose(const float* __restrict__ g,
                                                   float* __restrict__ out) {
    int t = blockIdx.x * 256 + threadIdx.x;     // 0 .. B*HW/4 - 1
    int m = t * 4;                               // base node
    int b = m >> 18;
    int hw = m & (HW - 1);
    const float* gb = g + (size_t)b * NC * HW + hw;
    float4 v[NC];
#pragma unroll
    for (int c = 0; c < NC; ++c) v[c] = *(const float4*)(gb + (size_t)c * HW);
    float4* dst = (float4*)(out + (size_t)m * NC);
#pragma unroll
    for (int j = 0; j < 4; ++j) {
        float q[NC];
#pragma unroll
        for (int c = 0; c < NC; ++c) q[c] = ((const float*)&v[c])[j];
#pragma unroll
        for (int k = 0; k < 4; ++k)
            dst[j * 4 + k] = make_float4(q[4 * k], q[4 * k + 1], q[4 * k + 2], q[4 * k + 3]);
    }
}

// Node-centric tiled edge kernel: block = 16x16 node tile, 1-node halo staged
// in LDS as packed bf16. Each thread computes its node's <=8 edges.
// edge_index output is reconstructed analytically (no ei input read).
__global__ __launch_bounds__(256) void k_edges_tiled(const float* __restrict__ nf,
                                                     float* __restrict__ out_ei,
                                                     float* __restrict__ out_attr,
                                                     int E) {
    __shared__ unsigned int lds[HALO * HALO * NSTRIDE];  // 42768 B

    int bx = blockIdx.x & 31, by = blockIdx.x >> 5;
    int h0 = by * TILE, w0 = bx * TILE;
    int tid = threadIdx.x;

    // ---- stage tile+halo: 18 rows x 18 cols x 4 batches, f32 -> packed bf16
    // unit u -> (row r, batch b, float4 f4 within the 18-node row segment)
    for (int u = tid; u < HALO * NB * (HALO * 4); u += 256) {   // 18*4*72 = 5184
        int f4  = u % (HALO * 4);      // 0..71
        int seg = u / (HALO * 4);      // 0..71
        int b   = seg & 3;
        int r   = seg >> 2;            // 0..17
        int hh  = h0 - 1 + r;
        int nw  = w0 - 1 + (f4 >> 2);
        int gn  = hh * GW + nw;
        gn = min(max(gn, 0), HW - 1);  // clamp; clamped values are never read
        const float4 src = *(const float4*)(nf + ((size_t)((b << 18) + gn)) * NC + (f4 & 3) * 4);
        int nl = r * HALO + (f4 >> 2);
        int base = nl * NSTRIDE + b * 8 + (f4 & 3) * 2;
        lds[base]     = pack2(src.x, src.y);
        lds[base + 1] = pack2(src.z, src.w);
    }
    __syncthreads();

    // ---- each thread owns node (h0+lr, w0+lc)
    int lr = tid >> 4, lc = tid & 15;
    int h = h0 + lr, w = w0 + lc;
    int n = h * GW + w;
    int nl_self = (lr + 1) * HALO + (lc + 1);

    unsigned int self[32];
#pragma unroll
    for (int j = 0; j < 32; ++j) self[j] = lds[nl_self * NSTRIDE + j];

    const int OFF_H[8] = {-1, -1, -1, 0, 0, 1, 1, 1};
    const int OFF_W[8] = {-1, 0, 1, -1, 1, -1, 0, 1};

    int P = edge_prefix(h, w);
    int cnt = 0;
    float src_f = (float)n;

#pragma unroll
    for (int k = 0; k < 8; ++k) {
        int dh = OFF_H[k], dw = OFF_W[k];
        int nh = h + dh, nw2 = w + dw;
        if ((unsigned)nh < GH && (unsigned)nw2 < GW) {
            int nl_n = (lr + 1 + dh) * HALO + (lc + 1 + dw);
            float acc = 0.0f;
#pragma unroll
            for (int j = 0; j < 32; ++j) {
                unsigned int a = self[j];
                unsigned int q = lds[nl_n * NSTRIDE + j];
                acc += fabsf(blo(a) - blo(q)) + fabsf(bhi(a) - bhi(q));
            }
            float dist = ((dh & dw) != 0) ? 1.41421356237f : 1.0f;
            int o = P + cnt;
            out_ei[o]     = src_f;
            out_ei[E + o] = (float)(n + dh * GW + dw);
            *(float2*)(out_attr + 2 * o) = make_float2(dist, acc * (1.0f / 64.0f));
            ++cnt;
        }
    }
}

extern "C" void kernel_launch(void* const* d_in, const int* in_sizes, int n_in,
                              void* d_out, int out_size, void* d_ws, size_t ws_size,
                              hipStream_t stream) {
    const float* g = (const float*)d_in[0];    // f32 grid (B,C,H,W)
    int E = in_sizes[1] / 2;                   // 2091012 (ei input not read)

    float* out      = (float*)d_out;
    float* nf_out   = out;                                   // (B*HW, C)  f32
    float* ei_out   = out + (size_t)NB * HW * NC;            // (2, E)     f32
    float* attr_out = ei_out + (size_t)2 * E;                // (E, 2)     f32

    k_transpose<<<(NB * HW / 4) / 256, 256, 0, stream>>>(g, nf_out);
    k_edges_tiled<<<(GH / TILE) * (GW / TILE), 256, 0, stream>>>(nf_out, ei_out, attr_out, E);
}

// Round 6
// 205.369 us; speedup vs baseline: 1.0809x; 1.0749x over previous
//
#include <hip/hip_runtime.h>

#define HW  (512 * 512)   // 262144 = 2^18
#define NC  16
#define NB  4
#define GW  512
#define GH  512
#define TILE 16
#define HALO 18           // TILE + 2
#define NSH  66           // ushorts per node in LDS (64 data + 2 pad)
#define NSU  33           // uint stride per node

// fp32 -> bf16 (RNE) + packed bf16 helpers
__device__ __forceinline__ unsigned int bfr(float f) {
    union { float f; unsigned int u; } v; v.f = f;
    return (v.u + 0x7fffu + ((v.u >> 16) & 1u)) >> 16;
}
__device__ __forceinline__ float blo(unsigned int u) {
    union { unsigned int u; float f; } v; v.u = u << 16; return v.f;
}
__device__ __forceinline__ float bhi(unsigned int u) {
    union { unsigned int u; float f; } v; v.u = u & 0xffff0000u; return v.f;
}

// edges strictly before node (h,w) in node-major, offset-ordered enumeration
__device__ __forceinline__ int edge_prefix(int h, int w) {
    if (h == 0) return (w == 0) ? 0 : 3 + 5 * (w - 1);
    int p = 2556 + 4090 * (h - 1);
    if (h == GH - 1) return p + ((w == 0) ? 0 : 3 + 5 * (w - 1));
    return p + ((w == 0) ? 0 : 5 + 8 * (w - 1));
}
__device__ __forceinline__ int degree(int h, int w) {
    int rh = 1 + (h > 0) + (h < GH - 1);
    int rw = 1 + (w > 0) + (w < GW - 1);
    return rh * rw - 1;
}

__global__ __launch_bounds__(256) void k_fused(const float* __restrict__ g,
                                               float* __restrict__ nf_out,
                                               float* __restrict__ ei_out,
                                               float* __restrict__ attr_out,
                                               int E) {
    __shared__ ushort nds[HALO * HALO * NSH];   // 42768 B: bf16 node features
    __shared__ float  fdbuf[TILE * TILE * 9];   //  9216 B: per-node fdiffs (pad 9)

    const int tid = threadIdx.x;
    const int bx = blockIdx.x & 31, by = blockIdx.x >> 5;
    const int h0 = by * TILE, w0 = bx * TILE;

    // ---- phase 1: stage 18x18 halo x 4 batches x 16 ch, f32 -> bf16 LDS
    // 18*18*4*16 = 20736 elements = 81 per thread; consecutive lanes read
    // consecutive w (72 B runs per (b,c,row)).
    for (int r = 0; r < 81; ++r) {
        int u   = r * 256 + tid;
        int col = u % HALO;
        int t1  = u / HALO;
        int row = t1 % HALO;
        int t2  = t1 / HALO;          // 0..63 = b*16 + c
        int c   = t2 & 15;
        int b   = t2 >> 4;
        int hh  = min(max(h0 - 1 + row, 0), GH - 1);   // clamped slots never read
        int ww  = min(max(w0 - 1 + col, 0), GW - 1);
        float val = g[(size_t)((b << 4) + c) * HW + (hh << 9) + ww];
        nds[(row * HALO + col) * NSH + (b << 4) + c] = (ushort)bfr(val);
    }
    __syncthreads();

    const unsigned int* ndu = (const unsigned int*)nds;

    // ---- phase 2: node_features out. Each wave writes exactly 1 KB contiguous
    // (16 nodes x 16 ch f32 of one tile-row, one batch) per round.
    #pragma unroll
    for (int r = 0; r < 16; ++r) {
        int o4 = r * 256 + tid;          // float4 slot: b(2) | node_local(8) | c4(2)
        int c4 = o4 & 3;
        int node_local = (o4 >> 2) & 255;
        int b  = o4 >> 10;
        int tr = node_local >> 4, tc = node_local & 15;
        int nl = (tr + 1) * HALO + (tc + 1);
        unsigned int u0 = ndu[nl * NSU + (b << 3) + c4 * 2];
        unsigned int u1 = ndu[nl * NSU + (b << 3) + c4 * 2 + 1];
        int n = (h0 + tr) * GW + (w0 + tc);
        float4* dst = (float4*)(nf_out + ((size_t)(b << 18) + n) * NC + c4 * 4);
        *dst = make_float4(blo(u0), bhi(u0), blo(u1), bhi(u1));
    }

    // ---- phase 3: per-node edge fdiffs -> fdbuf (no barrier needed before:
    // reads nds only, writes fdbuf only)
    {
        int tr = tid >> 4, tc = tid & 15;
        int h = h0 + tr, w = w0 + tc;
        int nl_self = (tr + 1) * HALO + (tc + 1);
        unsigned int self[32];
        #pragma unroll
        for (int j = 0; j < 32; ++j) self[j] = ndu[nl_self * NSU + j];

        const int OFF_H[8] = {-1, -1, -1, 0, 0, 1, 1, 1};
        const int OFF_W[8] = {-1, 0, 1, -1, 1, -1, 0, 1};
        int cnt = 0;
        #pragma unroll
        for (int k = 0; k < 8; ++k) {
            int nh = h + OFF_H[k], nw = w + OFF_W[k];
            if ((unsigned)nh < GH && (unsigned)nw < GW) {
                int nl_n = (tr + 1 + OFF_H[k]) * HALO + (tc + 1 + OFF_W[k]);
                float acc = 0.0f;
                #pragma unroll
                for (int j = 0; j < 32; ++j) {
                    unsigned int a = self[j], q = ndu[nl_n * NSU + j];
                    acc += fabsf(blo(a) - blo(q)) + fabsf(bhi(a) - bhi(q));
                }
                fdbuf[tid * 9 + cnt] = acc * (1.0f / 64.0f);
                ++cnt;
            }
        }
    }
    __syncthreads();

    // ---- phase 4: edge outputs, edge-major. One 128-slot chunk per tile-row;
    // each wave sits in one chunk -> uniform branches, lane-consecutive stores.
    #pragma unroll
    for (int r = 0; r < 8; ++r) {
        int u2    = r * 256 + tid;
        int chunk = u2 >> 7;             // tile row 0..15
        int e     = u2 & 127;
        int h     = h0 + chunk;
        int first = degree(h, w0);
        int mid   = degree(h, w0 + 1);
        int last  = degree(h, w0 + TILE - 1);
        int Lr    = first + 14 * mid + last;
        if (e < Lr) {
            int node_in_row, k;
            if (e < first) { node_in_row = 0; k = e; }
            else {
                int m = e - first;
                if (mid == 8) { node_in_row = 1 + (m >> 3); k = m & 7; }
                else          { int q = m / 5; node_in_row = 1 + q; k = m - 5 * q; }
            }
            int w = w0 + node_in_row;
            int n = h * GW + w;
            const int OFF_H[8] = {-1, -1, -1, 0, 0, 1, 1, 1};
            const int OFF_W[8] = {-1, 0, 1, -1, 1, -1, 0, 1};
            int idx = 0, cnt2 = 0;
            #pragma unroll
            for (int i = 0; i < 8; ++i) {
                bool ok = (unsigned)(h + OFF_H[i]) < GH && (unsigned)(w + OFF_W[i]) < GW;
                if (ok) { if (cnt2 == k) idx = i; ++cnt2; }
            }
            int dh = OFF_H[idx], dw = OFF_W[idx];
            float dist = (dh != 0 && dw != 0) ? 1.41421356237f : 1.0f;
            float fd = fdbuf[(chunk * 16 + node_in_row) * 9 + k];
            int o = edge_prefix(h, w0) + e;
            ei_out[o]     = (float)n;
            ei_out[E + o] = (float)(n + dh * GW + dw);
            *(float2*)(attr_out + 2 * (size_t)o) = make_float2(dist, fd);
        }
    }
}

extern "C" void kernel_launch(void* const* d_in, const int* in_sizes, int n_in,
                              void* d_out, int out_size, void* d_ws, size_t ws_size,
                              hipStream_t stream) {
    const float* g = (const float*)d_in[0];    // f32 grid (B,C,H,W)
    int E = in_sizes[1] / 2;                   // 2091012 (ei input not read)

    float* out      = (float*)d_out;
    float* nf_out   = out;                                   // (B*HW, C)  f32
    float* ei_out   = out + (size_t)NB * HW * NC;            // (2, E)     f32
    float* attr_out = ei_out + (size_t)2 * E;                // (E, 2)     f32

    k_fused<<<(GH / TILE) * (GW / TILE), 256, 0, stream>>>(g, nf_out, ei_out, attr_out, E);
}

// Round 7
// 186.914 us; speedup vs baseline: 1.1876x; 1.0987x over previous
//
#include <hip/hip_runtime.h>

#define HW  (512 * 512)   // 262144 = 2^18
#define NC  16
#define NB  4
#define GW  512
#define GH  512
#define TILE 16
#define HALO 18           // TILE + 2
#define NSU  12           // uints per node in LDS: 8 data (16 bf16) + 4 pad -> 48B, 16B-aligned

// fp32 -> bf16 (RNE) + packed bf16 helpers
__device__ __forceinline__ unsigned int bfr(float f) {
    union { float f; unsigned int u; } v; v.f = f;
    return (v.u + 0x7fffu + ((v.u >> 16) & 1u)) >> 16;
}
__device__ __forceinline__ float blo(unsigned int u) {
    union { unsigned int u; float f; } v; v.u = u << 16; return v.f;
}
__device__ __forceinline__ float bhi(unsigned int u) {
    union { unsigned int u; float f; } v; v.u = u & 0xffff0000u; return v.f;
}

// edges strictly before node (h,w) in node-major, offset-ordered enumeration
__device__ __forceinline__ int edge_prefix(int h, int w) {
    if (h == 0) return (w == 0) ? 0 : 3 + 5 * (w - 1);
    int p = 2556 + 4090 * (h - 1);
    if (h == GH - 1) return p + ((w == 0) ? 0 : 3 + 5 * (w - 1));
    return p + ((w == 0) ? 0 : 5 + 8 * (w - 1));
}
__device__ __forceinline__ int degree(int h, int w) {
    int rh = 1 + (h > 0) + (h < GH - 1);
    int rw = 1 + (w > 0) + (w < GW - 1);
    return rh * rw - 1;
}

__global__ __launch_bounds__(256) void k_fused(const float* __restrict__ g,
                                               float* __restrict__ nf_out,
                                               float* __restrict__ ei_out,
                                               float* __restrict__ attr_out,
                                               int E) {
    __shared__ unsigned int nds[HALO * HALO * NSU];   // 15552 B, bf16-packed node-major
    float* fdbuf = (float*)nds;                        // overlay after batch loop (9216 B)

    const int tid = threadIdx.x;
    const int bx = blockIdx.x & 31, by = blockIdx.x >> 5;
    const int h0 = by * TILE, w0 = bx * TILE;
    const int tr = tid >> 4, tc = tid & 15;

    const int OFF_H[8] = {-1, -1, -1, 0, 0, 1, 1, 1};
    const int OFF_W[8] = {-1, 0, 1, -1, 1, -1, 0, 1};

    float acc[8];
#pragma unroll
    for (int k = 0; k < 8; ++k) acc[k] = 0.0f;

    for (int b = 0; b < NB; ++b) {
        __syncthreads();   // previous batch's LDS reads complete before restage

        // ---- phase 1: stage batch b. Per slot: (c-pair, row, f4-window).
        // 8 c2 x 18 rows x 6 float4 = 864 slots; aligned 16B loads from 2 planes,
        // packed to bf16 pairs in-register, masked LDS b32 writes (node-major).
        for (int r = 0; r < 4; ++r) {
            int idx = r * 256 + tid;
            if (idx < 864) {
                int f4  = idx % 6;
                int t   = idx / 6;
                int row = t % 18;
                int c2  = t / 18;                         // 0..7 (channel pair)
                int hh  = min(max(h0 - 1 + row, 0), GH - 1);
                int gw  = min(max(w0 - 4 + 4 * f4, 0), GW - 4);
                const float* pA = g + (((size_t)(b * 16 + 2 * c2)) << 18) + (hh << 9) + gw;
                const float4 A = *(const float4*)pA;
                const float4 B = *(const float4*)(pA + HW);
#pragma unroll
                for (int j = 0; j < 4; ++j) {
                    int hc = 4 * f4 + j - 3;              // halo col: window pos - 3
                    if ((unsigned)hc < (unsigned)HALO) {
                        float a  = ((const float*)&A)[j];
                        float bb = ((const float*)&B)[j];
                        nds[(row * HALO + hc) * NSU + c2] = bfr(a) | (bfr(bb) << 16);
                    }
                }
            }
        }
        __syncthreads();

        // ---- phase 2: nf_out for batch b. 1024 float4 slots; each wave's 64
        // lanes store 1 KB contiguous.
#pragma unroll
        for (int s = 0; s < 4; ++s) {
            int o4 = s * 256 + tid;
            int c4 = o4 & 3;
            int nl256 = o4 >> 2;
            int pr = nl256 >> 4, pc = nl256 & 15;
            int nl = (pr + 1) * HALO + (pc + 1);
            unsigned int u0 = nds[nl * NSU + 2 * c4];
            unsigned int u1 = nds[nl * NSU + 2 * c4 + 1];
            int n = (h0 + pr) * GW + (w0 + pc);
            float4* dst = (float4*)(nf_out + (((size_t)b << 18) + n) * NC + 4 * c4);
            *dst = make_float4(blo(u0), bhi(u0), blo(u1), bhi(u1));
        }

        // ---- phase 3: accumulate 8 neighbor diffs (b128 fragment reads)
        {
            const uint4* p = (const uint4*)nds;
            int nl_self = (tr + 1) * HALO + (tc + 1);
            uint4 s0 = p[nl_self * 3];
            uint4 s1 = p[nl_self * 3 + 1];
#pragma unroll
            for (int k = 0; k < 8; ++k) {
                int nl_n = (tr + 1 + OFF_H[k]) * HALO + (tc + 1 + OFF_W[k]);
                uint4 n0 = p[nl_n * 3];
                uint4 n1 = p[nl_n * 3 + 1];
                float a = 0.0f;
                a += fabsf(blo(s0.x) - blo(n0.x)) + fabsf(bhi(s0.x) - bhi(n0.x));
                a += fabsf(blo(s0.y) - blo(n0.y)) + fabsf(bhi(s0.y) - bhi(n0.y));
                a += fabsf(blo(s0.z) - blo(n0.z)) + fabsf(bhi(s0.z) - bhi(n0.z));
                a += fabsf(blo(s0.w) - blo(n0.w)) + fabsf(bhi(s0.w) - bhi(n0.w));
                a += fabsf(blo(s1.x) - blo(n1.x)) + fabsf(bhi(s1.x) - bhi(n1.x));
                a += fabsf(blo(s1.y) - blo(n1.y)) + fabsf(bhi(s1.y) - bhi(n1.y));
                a += fabsf(blo(s1.z) - blo(n1.z)) + fabsf(bhi(s1.z) - bhi(n1.z));
                a += fabsf(blo(s1.w) - blo(n1.w)) + fabsf(bhi(s1.w) - bhi(n1.w));
                acc[k] += a;
            }
        }
    }

    __syncthreads();   // all phase-3 reads of nds complete -> overlay fdbuf

    // ---- write per-node fdiffs (valid-packed, pad-9 stride)
    {
        int h = h0 + tr, w = w0 + tc;
        int cnt = 0;
#pragma unroll
        for (int k = 0; k < 8; ++k) {
            if ((unsigned)(h + OFF_H[k]) < (unsigned)GH &&
                (unsigned)(w + OFF_W[k]) < (unsigned)GW) {
                fdbuf[tid * 9 + cnt] = acc[k] * (1.0f / 64.0f);
                ++cnt;
            }
        }
    }
    __syncthreads();

    // ---- phase 4: edge outputs, edge-major (lane-consecutive stores)
#pragma unroll
    for (int r = 0; r < 8; ++r) {
        int u2    = r * 256 + tid;
        int chunk = u2 >> 7;             // tile row 0..15
        int e     = u2 & 127;
        int h     = h0 + chunk;
        int first = degree(h, w0);
        int mid   = degree(h, w0 + 1);
        int last  = degree(h, w0 + TILE - 1);
        int Lr    = first + 14 * mid + last;
        if (e < Lr) {
            int node_in_row, k;
            if (e < first) { node_in_row = 0; k = e; }
            else {
                int m = e - first;
                if (mid == 8) { node_in_row = 1 + (m >> 3); k = m & 7; }
                else          { int q = m / 5; node_in_row = 1 + q; k = m - 5 * q; }
            }
            int w = w0 + node_in_row;
            int n = h * GW + w;
            int idx = 0, cnt2 = 0;
#pragma unroll
            for (int i = 0; i < 8; ++i) {
                bool ok = (unsigned)(h + OFF_H[i]) < (unsigned)GH &&
                          (unsigned)(w + OFF_W[i]) < (unsigned)GW;
                if (ok) { if (cnt2 == k) idx = i; ++cnt2; }
            }
            int dh = OFF_H[idx], dw = OFF_W[idx];
            float dist = (dh != 0 && dw != 0) ? 1.41421356237f : 1.0f;
            float fd = fdbuf[(chunk * 16 + node_in_row) * 9 + k];
            int o = edge_prefix(h, w0) + e;
            ei_out[o]     = (float)n;
            ei_out[E + o] = (float)(n + dh * GW + dw);
            *(float2*)(attr_out + 2 * (size_t)o) = make_float2(dist, fd);
        }
    }
}

extern "C" void kernel_launch(void* const* d_in, const int* in_sizes, int n_in,
                              void* d_out, int out_size, void* d_ws, size_t ws_size,
                              hipStream_t stream) {
    const float* g = (const float*)d_in[0];    // f32 grid (B,C,H,W)
    int E = in_sizes[1] / 2;                   // 2091012 (ei input not read)

    float* out      = (float*)d_out;
    float* nf_out   = out;                                   // (B*HW, C)  f32
    float* ei_out   = out + (size_t)NB * HW * NC;            // (2, E)     f32
    float* attr_out = ei_out + (size_t)2 * E;                // (E, 2)     f32

    k_fused<<<(GH / TILE) * (GW / TILE), 256, 0, stream>>>(g, nf_out, ei_out, attr_out, E);
}